// Round 13
// baseline (98.194 us; speedup 1.0000x reference)
//
#include <hip/hip_runtime.h>

// Problem constants
#define NB     64      // batch
#define TT     2048    // time
#define INQ    8       // input size
#define CC     2       // channels
#define MM     10      // hidden m
#define ROWP   12      // padded row floats (48 B)
#define MATS   124     // matrix stride in LDS tree (124%32=28)
#define SKST   12      // skq row stride floats (48 B, b128-aligned)
#define BLK    256     // threads per block (4 waves) -- unlocks VGPR headroom
#define SEGS   96      // 48 groups x 2 streams
#define SLEN   11      // steps per segment (padded timeline 2112 = 2*96*11)
#define NCHK   2       // chunks per chain -> grid 256 = 1 block/CU
#define NCHAIN (NB*CC)
#define GSLOT  240     // scratch floats per group (2 streams x 2 parities x 60)

typedef float v2f __attribute__((ext_vector_type(2)));

static_assert(SEGS * MATS >= 49 * GSLOT, "scratch overlay must fit tree buffer");

// Upper-triangle index for (k,j), k<j, into 45-element array
__device__ __forceinline__ constexpr int triIdx(int k, int j) {
    return k * 10 + j - ((k + 1) * (k + 2)) / 2;
}

// One Taylor row-stream, packed pair of rows: t = S*G; A = t; R += cj*t.
// Row r of S*G depends only on row r of S -> in-place safe (S may alias A).
__device__ __forceinline__ void trow_pk(const float* __restrict__ Tri,
                                        v2f* A, v2f* R, const v2f* S, float cj) {
    v2f t[MM];
    t[0] = -S[1] * Tri[triIdx(0, 1)];
    #pragma unroll
    for (int j = 1; j < MM; ++j) t[j] = S[0] * Tri[triIdx(0, j)];
    #pragma unroll
    for (int k = 1; k < MM; ++k) {
        const v2f a = S[k];
        #pragma unroll
        for (int j = 0; j < MM; ++j) {
            if (k == j) continue;
            if (j == 0 && k == 1) continue;
            if (j > k) t[j] += a * Tri[triIdx(k, j)];
            else       t[j] -= a * Tri[triIdx(j, k)];
        }
    }
    #pragma unroll
    for (int j = 0; j < MM; ++j) { A[j] = t[j]; R[j] += cj * t[j]; }
}

// KTAY=5 dual-stream Taylor: A and B interleaved at trow granularity so
// stream B's independent FMAs fill stream A's dependency/wait gaps.
__device__ __forceinline__ void taylor5_dual(const float* __restrict__ TriA, v2f* RA,
                                             const float* __restrict__ TriB, v2f* RB) {
    __builtin_amdgcn_s_setprio(1);
    v2f Aa[MM], Ab[MM];
    trow_pk(TriA, Aa, RA, RA, 1.0f);
    trow_pk(TriB, Ab, RB, RB, 1.0f);
    trow_pk(TriA, Aa, RA, Aa, 0.5f);
    trow_pk(TriB, Ab, RB, Ab, 0.5f);
    trow_pk(TriA, Aa, RA, Aa, 0.16666667f);
    trow_pk(TriB, Ab, RB, Ab, 0.16666667f);
    trow_pk(TriA, Aa, RA, Aa, 0.041666668f);
    trow_pk(TriB, Ab, RB, Ab, 0.041666668f);
    trow_pk(TriA, Aa, RA, Aa, 0.0083333338f);
    trow_pk(TriB, Ab, RB, Ab, 0.0083333338f);
    __builtin_amdgcn_s_setprio(0);
}

// tvv for one step: clamped x loads, dx, 9 dot-products against the
// REGISTER-resident skq rows (sg[2i], sg[2i+1] = row i halves).
__device__ __forceinline__ void compute_tvv(const float4* __restrict__ px, int t,
                                            const float4* __restrict__ sg,
                                            float* __restrict__ tvv) {
    const int tc = (t     > TT - 1) ? TT - 1 : t;
    const int t1 = (t + 1 > TT - 1) ? TT - 1 : t + 1;
    const float4 a0 = px[2 * tc], a1 = px[2 * tc + 1];
    const float4 b0 = px[2 * t1], b1 = px[2 * t1 + 1];
    float dx[INQ];
    dx[0] = b0.x - a0.x; dx[1] = b0.y - a0.y;
    dx[2] = b0.z - a0.z; dx[3] = b0.w - a0.w;
    dx[4] = b1.x - a1.x; dx[5] = b1.y - a1.y;
    dx[6] = b1.z - a1.z; dx[7] = b1.w - a1.w;
    #pragma unroll
    for (int i = 0; i < 9; ++i) {
        const float4 s0 = sg[2 * i];
        const float4 s1 = sg[2 * i + 1];
        tvv[i] = dx[0] * s0.x + dx[1] * s0.y + dx[2] * s0.z + dx[3] * s0.w
               + dx[4] * s1.x + dx[5] * s1.y + dx[6] * s1.z + dx[7] * s1.w;
    }
}

// Stage 9 tvv to the group scratch slot: 2 b128 + 1 b32 (48B-aligned lane slot).
__device__ __forceinline__ void store_tvv(float* __restrict__ dst, int r,
                                          const float* __restrict__ tvv) {
    *reinterpret_cast<float4*>(dst + 12 * r)     = make_float4(tvv[0], tvv[1], tvv[2], tvv[3]);
    *reinterpret_cast<float4*>(dst + 12 * r + 4) = make_float4(tvv[4], tvv[5], tvv[6], tvv[7]);
    dst[12 * r + 8] = tvv[8];
}

// Gather the group's 45 entries: 5 x (b128, b128, b32).
__device__ __forceinline__ void load_tri(const float* __restrict__ src,
                                         float* __restrict__ Tri) {
    #pragma unroll
    for (int q2 = 0; q2 < 5; ++q2) {
        const float4 u0 = *reinterpret_cast<const float4*>(src + 12 * q2);
        const float4 u1 = *reinterpret_cast<const float4*>(src + 12 * q2 + 4);
        const float  u2 = src[12 * q2 + 8];
        Tri[9 * q2 + 0] = u0.x; Tri[9 * q2 + 1] = u0.y;
        Tri[9 * q2 + 2] = u0.z; Tri[9 * q2 + 3] = u0.w;
        Tri[9 * q2 + 4] = u1.x; Tri[9 * q2 + 5] = u1.y;
        Tri[9 * q2 + 6] = u1.z; Tri[9 * q2 + 7] = u1.w;
        Tri[9 * q2 + 8] = u2;
    }
}

// 2-lane pair combine: buf[ls] <- buf[ls] * buf[rs] (pq = which 5-row half)
__device__ __forceinline__ void pair_combine(float* buf_s, int ls, int rs, int pq) {
    float lrow[5][MM];
    #pragma unroll
    for (int r = 0; r < 5; ++r) {
        const float4* lr = reinterpret_cast<const float4*>(
            &buf_s[ls * MATS + (pq * 5 + r) * ROWP]);
        const float4 a = lr[0], b = lr[1], c4 = lr[2];
        lrow[r][0] = a.x;  lrow[r][1] = a.y;  lrow[r][2] = a.z;  lrow[r][3] = a.w;
        lrow[r][4] = b.x;  lrow[r][5] = b.y;  lrow[r][6] = b.z;  lrow[r][7] = b.w;
        lrow[r][8] = c4.x; lrow[r][9] = c4.y;
    }
    float d[5][MM];
    #pragma unroll
    for (int r = 0; r < 5; ++r)
        #pragma unroll
        for (int j = 0; j < MM; ++j)
            d[r][j] = 0.0f;
    #pragma unroll
    for (int k = 0; k < MM; ++k) {
        const float4* rr = reinterpret_cast<const float4*>(&buf_s[rs * MATS + k * ROWP]);
        const float4 a = rr[0], b = rr[1], c4 = rr[2];
        float rrow[MM];
        rrow[0] = a.x;  rrow[1] = a.y;  rrow[2] = a.z;  rrow[3] = a.w;
        rrow[4] = b.x;  rrow[5] = b.y;  rrow[6] = b.z;  rrow[7] = b.w;
        rrow[8] = c4.x; rrow[9] = c4.y;
        #pragma unroll
        for (int r = 0; r < 5; ++r) {
            const float lv = lrow[r][k];
            #pragma unroll
            for (int j = 0; j < MM; ++j)
                d[r][j] += lv * rrow[j];
        }
    }
    float* dst = &buf_s[ls * MATS + pq * 5 * ROWP];
    #pragma unroll
    for (int r = 0; r < 5; ++r) {
        float4* drow = reinterpret_cast<float4*>(dst + r * ROWP);
        drow[0] = make_float4(d[r][0], d[r][1], d[r][2], d[r][3]);
        drow[1] = make_float4(d[r][4], d[r][5], d[r][6], d[r][7]);
        drow[2] = make_float4(d[r][8], d[r][9], 0.0f, 0.0f);
    }
}

// r24: ILP over TLP. Measured: ~48% of each step is stall that neither
// extra waves (r17/r22 null) nor fewer LDS ops (r23: half the ops, -4%)
// fills -- waves stall in lockstep at the same phases. Fix: TWO
// independent segment-streams per lane (segs 2g, 2g+1), trow-granular
// interleave -> stream B issues while stream A waits. BLK=256 enables it:
// r19 proved BLK=512 is compiler-capped at 128 VGPR; BLK=256 compiles
// freely (r12: 152). Peak live ~280 regs, fine at 1 wave/SIMD (TLP is
// proven worthless here; m08: spill only near ~500). Same 96 segs/block,
// same tree, same total work; grid 256 = 1 block/CU; dev_tree2 unchanged.
// Scratch: 240 floats/group (2 streams x 2 parities x 60), 49 slots =
// 11760 <= 11904 overlay. Math bit-identical per segment (absmax must
// stay 0.0078125). Litmus: FETCH ~4.3MB (>20MB = spill -> drop sg hoist).
// OccupancyPercent ~6 is EXPECTED (4 waves/CU), not a failure signal.
__global__ __launch_bounds__(BLK)
void dev_serial(const float* __restrict__ x,
                const float* __restrict__ A,
                float* __restrict__ ws)
{
    __shared__ __align__(16) float skq_s[45 * SKST];    // 2160 B, e-major
    __shared__ __align__(16) float buf_s[SEGS * MATS];  // 47616 B tree buffer

    const int tid   = threadIdx.x;
    const int chain = blockIdx.x >> 1;   // / NCHK
    const int qt    = blockIdx.x & 1;
    const int n     = chain >> 1;        // / CC
    const int c     = chain & 1;

    // skq[e][ip] = sk-tri entry e of input dim ip (channel c). 360 entries.
    for (int e4 = tid; e4 < 45 * 8; e4 += BLK) {
        const int e  = e4 >> 3;
        const int ip = e4 & 7;
        int k = 0, r2 = e;
        while (r2 >= 9 - k) { r2 -= (9 - k); ++k; }
        const int j = k + 1 + r2;
        const float* Ab = A + (size_t)(c * INQ + ip) * (MM * MM);
        skq_s[e * SKST + ip] = Ab[k * MM + j] - Ab[j * MM + k];
    }
    __syncthreads();

    const int wv  = tid >> 6;            // wave 0..3
    const int wl  = tid & 63;            // lane in wave
    const int g   = wl / 5;              // group 0..11 (12 = inactive tail)
    const int r   = wl - 5 * g;          // role 0..4 -> owns rows {2r, 2r+1}
    const bool act = (wl < 60);
    const int grp = wv * 12 + g;         // 0..47 active (48 = dump)
    const int segA = grp * 2;            // this lane's two segments
    const int segB = grp * 2 + 1;
    const int p0  = 2 * r;

    // Hoist this lane's 9 skq rows into registers (shared by both streams).
    float4 sg[18];
    {
        const float* srow = &skq_s[(9 * r) * SKST];
        #pragma unroll
        for (int i = 0; i < 9; ++i) {
            sg[2 * i]     = *reinterpret_cast<const float4*>(srow + i * SKST);
            sg[2 * i + 1] = *reinterpret_cast<const float4*>(srow + i * SKST + 4);
        }
    }

    // Scratch: 240 floats/group = stream A parities {0,60}, B {120,180}.
    // Inactive lanes write to dump slot 48; reads give garbage, discarded.
    float* slot  = &buf_s[grp * GSLOT];
    float* slotw = act ? slot : &buf_s[48 * GSLOT];

    v2f RA[MM], RB[MM];
    #pragma unroll
    for (int j = 0; j < MM; ++j) {
        RA[j] = (v2f){ (j == p0) ? 1.0f : 0.0f, (j == p0 + 1) ? 1.0f : 0.0f };
        RB[j] = RA[j];
    }

    const float4* px = reinterpret_cast<const float4*>(x + (size_t)n * TT * INQ);
    const int t0A = qt * (SEGS * SLEN) + segA * SLEN;   // padded timeline < 2112
    const int t0B = t0A + SLEN;

    // Dual software pipeline over the scratch parity buffers.
    float tvvA[9], tvvB[9];
    compute_tvv(px, t0A, sg, tvvA);
    compute_tvv(px, t0B, sg, tvvB);
    store_tvv(slotw,       r, tvvA);     // A parity 0
    store_tvv(slotw + 120, r, tvvB);     // B parity 0

    #pragma unroll 1
    for (int s = 0; s < SLEN - 1; ++s) {
        const int rpar = (s & 1) * 60;
        float TriA[45], TriB[45];
        load_tri(slot + rpar,       TriA);       // written 1 burst ago
        load_tri(slot + 120 + rpar, TriB);
        compute_tvv(px, t0A + s + 1, sg, tvvA);  // hides the read latency
        compute_tvv(px, t0B + s + 1, sg, tvvB);
        store_tvv(slotw + (60 - rpar),       r, tvvA);  // opposite parity
        store_tvv(slotw + 120 + (60 - rpar), r, tvvB);
        taylor5_dual(TriA, RA, TriB, RB);
    }
    {
        const int rpar = ((SLEN - 1) & 1) * 60;
        float TriA[45], TriB[45];
        load_tri(slot + rpar,       TriA);
        load_tri(slot + 120 + rpar, TriB);
        taylor5_dual(TriA, RA, TriB, RB);
    }

    // Scratch phase over; buf_s becomes the tree buffer.
    __syncthreads();

    // Store both segment products: packed row-pairs per lane.
    if (act) {
        float* dstA = &buf_s[segA * MATS];
        float4* a0 = reinterpret_cast<float4*>(dstA + p0 * ROWP);
        a0[0] = make_float4(RA[0].x, RA[1].x, RA[2].x, RA[3].x);
        a0[1] = make_float4(RA[4].x, RA[5].x, RA[6].x, RA[7].x);
        a0[2] = make_float4(RA[8].x, RA[9].x, 0.0f, 0.0f);
        float4* a1 = reinterpret_cast<float4*>(dstA + (p0 + 1) * ROWP);
        a1[0] = make_float4(RA[0].y, RA[1].y, RA[2].y, RA[3].y);
        a1[1] = make_float4(RA[4].y, RA[5].y, RA[6].y, RA[7].y);
        a1[2] = make_float4(RA[8].y, RA[9].y, 0.0f, 0.0f);
        float* dstB = &buf_s[segB * MATS];
        float4* b0 = reinterpret_cast<float4*>(dstB + p0 * ROWP);
        b0[0] = make_float4(RB[0].x, RB[1].x, RB[2].x, RB[3].x);
        b0[1] = make_float4(RB[4].x, RB[5].x, RB[6].x, RB[7].x);
        b0[2] = make_float4(RB[8].x, RB[9].x, 0.0f, 0.0f);
        float4* b1 = reinterpret_cast<float4*>(dstB + (p0 + 1) * ROWP);
        b1[0] = make_float4(RB[0].y, RB[1].y, RB[2].y, RB[3].y);
        b1[1] = make_float4(RB[4].y, RB[5].y, RB[6].y, RB[7].y);
        b1[2] = make_float4(RB[8].y, RB[9].y, 0.0f, 0.0f);
    }
    __syncthreads();

    // Dyadic tree on 96 leaves: spans 2..32 -> products at {0,32,64},
    // then (0*32) and (0*64) sequential tail (time order preserved).
    #pragma unroll 1
    for (int span = 2; span <= 32; span <<= 1) {
        const int np = SEGS / span;
        if (tid < 2 * np) {
            const int pr = tid >> 1;
            const int pq = tid & 1;
            pair_combine(buf_s, pr * span, pr * span + (span >> 1), pq);
        }
        __syncthreads();
    }
    if (tid < 2) pair_combine(buf_s, 0, 32, tid);
    __syncthreads();
    if (tid < 2) pair_combine(buf_s, 0, 64, tid);
    __syncthreads();

    // Chunk product -> ws, padded 120 floats at (chain*NCHK + qt)
    if (tid < 30) {
        const float4 v = reinterpret_cast<const float4*>(buf_s)[tid];
        reinterpret_cast<float4*>(ws)[((size_t)chain * NCHK + qt) * 30 + tid] = v;
    }
}

// K2: one block per chain; combine its 2 chunk products (time order)
__global__ __launch_bounds__(256)
void dev_tree2(const float* __restrict__ ws, float* __restrict__ out)
{
    __shared__ __align__(16) float buf_s[2 * MATS];
    const int tid   = threadIdx.x;
    const int chain = blockIdx.x;

    if (tid < 60) {
        const int m  = tid / 30;
        const int o4 = tid - m * 30;
        const float4 v = reinterpret_cast<const float4*>(ws)[((size_t)chain * 2 + m) * 30 + o4];
        reinterpret_cast<float4*>(&buf_s[m * MATS])[o4] = v;
    }
    __syncthreads();

    if (tid < 2)
        pair_combine(buf_s, 0, 1, tid);
    __syncthreads();

    if (tid < 100) {
        const int i = tid / 10;
        const int j = tid - i * 10;
        out[(size_t)chain * 100 + tid] = buf_s[i * ROWP + j];
    }
}

extern "C" void kernel_launch(void* const* d_in, const int* in_sizes, int n_in,
                              void* d_out, int out_size, void* d_ws, size_t ws_size,
                              hipStream_t stream) {
    (void)in_sizes; (void)n_in; (void)out_size; (void)ws_size;
    const float* x = (const float*)d_in[0];  // (64, 2048, 8)
    const float* A = (const float*)d_in[1];  // (2, 8, 10, 10)
    float* out = (float*)d_out;              // (64, 2, 10, 10)
    float* ws  = (float*)d_ws;               // 256 mats * 480 B = 122,880 B

    dev_serial<<<dim3(NCHAIN * NCHK), dim3(BLK), 0, stream>>>(x, A, ws);
    dev_tree2<<<dim3(NCHAIN), dim3(256), 0, stream>>>(ws, out);
}

// Round 15
// 92.434 us; speedup vs baseline: 1.0623x; 1.0623x over previous
//
#include <hip/hip_runtime.h>

// Problem constants
#define NB     64      // batch
#define TT     2048    // time
#define INQ    8       // input size
#define CC     2       // channels
#define MM     10      // hidden m
#define ROWP   12      // padded row floats (48 B)
#define MATS   124     // matrix stride in LDS tree (124%32=28)
#define SKST   12      // skq row stride floats (48 B, b128-aligned)
#define BLK    512     // threads per block (8 waves)
#define SEGS   96      // 8 waves * 12 five-lane groups
#define SLEN   11      // steps per segment (padded timeline 2112 = 2*96*11, 3% pad)
#define NCHK   2       // chunks per chain -> grid 256 = 1 block/CU
#define NCHAIN (NB*CC)
#define SLOT   124     // scratch slot floats per group (2 parities x 60 + 4 pad)
                       // 124%32=28 -> 12 group bases spread over 8 banks sets
                       // (old 120: stride 24 -> only 4 sets -> 3-way conflicts)

typedef float v2f __attribute__((ext_vector_type(2)));

static_assert(SEGS * SLOT <= SEGS * MATS, "scratch overlay must fit tree buffer");

// Upper-triangle index for (k,j), k<j, into 45-element array
__device__ __forceinline__ constexpr int triIdx(int k, int j) {
    return k * 10 + j - ((k + 1) * (k + 2)) / 2;
}

// One Taylor row-stream, packed pair of rows: t = S*G; A = t; R += cj*t.
// Row r of S*G depends only on row r of S -> in-place safe (S may alias A).
__device__ __forceinline__ void trow_pk(const float* __restrict__ Tri,
                                        v2f* A, v2f* R, const v2f* S, float cj) {
    v2f t[MM];
    t[0] = -S[1] * Tri[triIdx(0, 1)];
    #pragma unroll
    for (int j = 1; j < MM; ++j) t[j] = S[0] * Tri[triIdx(0, j)];
    #pragma unroll
    for (int k = 1; k < MM; ++k) {
        const v2f a = S[k];
        #pragma unroll
        for (int j = 0; j < MM; ++j) {
            if (k == j) continue;
            if (j == 0 && k == 1) continue;
            if (j > k) t[j] += a * Tri[triIdx(k, j)];
            else       t[j] -= a * Tri[triIdx(j, k)];
        }
    }
    #pragma unroll
    for (int j = 0; j < MM; ++j) { A[j] = t[j]; R[j] += cj * t[j]; }
}

// KTAY=5 Taylor burst (r25's KTAY=4 FAILED accuracy: 0.0273 > 0.0195;
// the theta^5/120 truncation is systematic-sign and accumulates ~4x
// faster than the sqrt(N) model. KTAY=5 is permanent.)
__device__ __forceinline__ void taylor5(const float* __restrict__ Tri, v2f* R01) {
    __builtin_amdgcn_s_setprio(1);
    v2f A01[MM];
    trow_pk(Tri, A01, R01, R01, 1.0f);
    trow_pk(Tri, A01, R01, A01, 0.5f);
    trow_pk(Tri, A01, R01, A01, 0.16666667f);
    trow_pk(Tri, A01, R01, A01, 0.041666668f);
    trow_pk(Tri, A01, R01, A01, 0.0083333338f);
    __builtin_amdgcn_s_setprio(0);
}

// tvv with x cur/nxt rotation: load only x[tn] (clamped), dx = nxt - cur,
// cur <- nxt. Halves x loads and issues the load at iteration top (gets
// load_tri + taylor worth of latency slack). Bit-identical dx by induction.
__device__ __forceinline__ void compute_tvv_rot(const float4* __restrict__ px, int tn,
                                                float4& cur0, float4& cur1,
                                                const float4* __restrict__ sg,
                                                float* __restrict__ tvv) {
    const int tc = (tn > TT - 1) ? TT - 1 : tn;
    const float4 b0 = px[2 * tc], b1 = px[2 * tc + 1];
    float dx[INQ];
    dx[0] = b0.x - cur0.x; dx[1] = b0.y - cur0.y;
    dx[2] = b0.z - cur0.z; dx[3] = b0.w - cur0.w;
    dx[4] = b1.x - cur1.x; dx[5] = b1.y - cur1.y;
    dx[6] = b1.z - cur1.z; dx[7] = b1.w - cur1.w;
    cur0 = b0; cur1 = b1;
    #pragma unroll
    for (int i = 0; i < 9; ++i) {
        const float4 s0 = sg[2 * i];
        const float4 s1 = sg[2 * i + 1];
        tvv[i] = dx[0] * s0.x + dx[1] * s0.y + dx[2] * s0.z + dx[3] * s0.w
               + dx[4] * s1.x + dx[5] * s1.y + dx[6] * s1.z + dx[7] * s1.w;
    }
}

// Stage 9 tvv to the group scratch slot: 2 b128 + 1 b32 (48B-aligned lane slot).
__device__ __forceinline__ void store_tvv(float* __restrict__ dst, int r,
                                          const float* __restrict__ tvv) {
    *reinterpret_cast<float4*>(dst + 12 * r)     = make_float4(tvv[0], tvv[1], tvv[2], tvv[3]);
    *reinterpret_cast<float4*>(dst + 12 * r + 4) = make_float4(tvv[4], tvv[5], tvv[6], tvv[7]);
    dst[12 * r + 8] = tvv[8];
}

// Gather the group's 45 entries: 5 x (b128, b128, b32).
__device__ __forceinline__ void load_tri(const float* __restrict__ src,
                                         float* __restrict__ Tri) {
    #pragma unroll
    for (int q2 = 0; q2 < 5; ++q2) {
        const float4 u0 = *reinterpret_cast<const float4*>(src + 12 * q2);
        const float4 u1 = *reinterpret_cast<const float4*>(src + 12 * q2 + 4);
        const float  u2 = src[12 * q2 + 8];
        Tri[9 * q2 + 0] = u0.x; Tri[9 * q2 + 1] = u0.y;
        Tri[9 * q2 + 2] = u0.z; Tri[9 * q2 + 3] = u0.w;
        Tri[9 * q2 + 4] = u1.x; Tri[9 * q2 + 5] = u1.y;
        Tri[9 * q2 + 6] = u1.z; Tri[9 * q2 + 7] = u1.w;
        Tri[9 * q2 + 8] = u2;
    }
}

// 2-lane pair combine: buf[ls] <- buf[ls] * buf[rs] (pq = which 5-row half)
__device__ __forceinline__ void pair_combine(float* buf_s, int ls, int rs, int pq) {
    float lrow[5][MM];
    #pragma unroll
    for (int r = 0; r < 5; ++r) {
        const float4* lr = reinterpret_cast<const float4*>(
            &buf_s[ls * MATS + (pq * 5 + r) * ROWP]);
        const float4 a = lr[0], b = lr[1], c4 = lr[2];
        lrow[r][0] = a.x;  lrow[r][1] = a.y;  lrow[r][2] = a.z;  lrow[r][3] = a.w;
        lrow[r][4] = b.x;  lrow[r][5] = b.y;  lrow[r][6] = b.z;  lrow[r][7] = b.w;
        lrow[r][8] = c4.x; lrow[r][9] = c4.y;
    }
    float d[5][MM];
    #pragma unroll
    for (int r = 0; r < 5; ++r)
        #pragma unroll
        for (int j = 0; j < MM; ++j)
            d[r][j] = 0.0f;
    #pragma unroll
    for (int k = 0; k < MM; ++k) {
        const float4* rr = reinterpret_cast<const float4*>(&buf_s[rs * MATS + k * ROWP]);
        const float4 a = rr[0], b = rr[1], c4 = rr[2];
        float rrow[MM];
        rrow[0] = a.x;  rrow[1] = a.y;  rrow[2] = a.z;  rrow[3] = a.w;
        rrow[4] = b.x;  rrow[5] = b.y;  rrow[6] = b.z;  rrow[7] = b.w;
        rrow[8] = c4.x; rrow[9] = c4.y;
        #pragma unroll
        for (int r = 0; r < 5; ++r) {
            const float lv = lrow[r][k];
            #pragma unroll
            for (int j = 0; j < MM; ++j)
                d[r][j] += lv * rrow[j];
        }
    }
    float* dst = &buf_s[ls * MATS + pq * 5 * ROWP];
    #pragma unroll
    for (int r = 0; r < 5; ++r) {
        float4* drow = reinterpret_cast<float4*>(dst + r * ROWP);
        drow[0] = make_float4(d[r][0], d[r][1], d[r][2], d[r][3]);
        drow[1] = make_float4(d[r][4], d[r][5], d[r][6], d[r][7]);
        drow[2] = make_float4(d[r][8], d[r][9], 0.0f, 0.0f);
    }
}

// r26: REVERT KTAY=4 (accuracy fail) -> exact r23 math (absmax 0.0078125)
// + two stall-targeted micro-fixes: (1) x cur/nxt rotation: 2 instead of
// 4 global b128/step, load issued at iteration top (+~8 VGPR, est 112 <
// 128 compiler cap for 512-thr blocks); (2) SLOT 120->124: group scratch
// stride 28 mod 32 (like MATS) -> 8 distinct bank-base sets for 12 groups
// instead of 4 (3-way -> ~1.5-way, free per m136). Inactive lanes use a
// dedicated dump buffer (old buf_s aliasing would go OOB at SLOT=124).
// Occupancy/TLP/ILP levers are all measured-dead (r17/r22/r24); this is
// the last latency trim on the proven structure.
__global__ __launch_bounds__(BLK, 1)
void dev_serial(const float* __restrict__ x,
                const float* __restrict__ A,
                float* __restrict__ ws)
{
    __shared__ __align__(16) float skq_s[45 * SKST];    // 2160 B, e-major
    __shared__ __align__(16) float buf_s[SEGS * MATS];  // 47616 B tree buffer
    __shared__ __align__(16) float dump_s[120];         // inactive-lane scratch

    const int tid   = threadIdx.x;
    const int chain = blockIdx.x >> 1;   // / NCHK
    const int qt    = blockIdx.x & 1;
    const int n     = chain >> 1;        // / CC
    const int c     = chain & 1;

    // skq[e][ip] = sk-tri entry e of input dim ip (channel c). 360 entries.
    if (tid < 45 * 8) {
        const int e  = tid >> 3;
        const int ip = tid & 7;
        int k = 0, r2 = e;
        while (r2 >= 9 - k) { r2 -= (9 - k); ++k; }
        const int j = k + 1 + r2;
        const float* Ab = A + (size_t)(c * INQ + ip) * (MM * MM);
        skq_s[e * SKST + ip] = Ab[k * MM + j] - Ab[j * MM + k];
    }
    __syncthreads();

    const int wv  = tid >> 6;            // wave 0..7
    const int wl  = tid & 63;            // lane in wave
    const int g   = wl / 5;              // group 0..11 (12 = inactive tail)
    const int r   = wl - 5 * g;          // role 0..4 -> owns rows {2r, 2r+1}
    const bool act = (wl < 60);
    const int seg = wv * 12 + g;         // 0..95 active
    const int p0  = 2 * r;

    // Hoist this lane's 9 skq rows into registers (loop-invariant).
    float4 sg[18];
    {
        const float* srow = &skq_s[(9 * r) * SKST];
        #pragma unroll
        for (int i = 0; i < 9; ++i) {
            sg[2 * i]     = *reinterpret_cast<const float4*>(srow + i * SKST);
            sg[2 * i + 1] = *reinterpret_cast<const float4*>(srow + i * SKST + 4);
        }
    }

    // Scratch slot (124 floats: parities at 0/60, 4 pad). Inactive lanes
    // (g==12) read AND write the dump buffer -- garbage in, discarded out.
    float* slot  = act ? &buf_s[seg * SLOT] : dump_s;
    float* slotw = slot;

    v2f R01[MM];
    #pragma unroll
    for (int j = 0; j < MM; ++j)
        R01[j] = (v2f){ (j == p0) ? 1.0f : 0.0f, (j == p0 + 1) ? 1.0f : 0.0f };

    const float4* px = reinterpret_cast<const float4*>(x + (size_t)n * TT * INQ);
    const int t0 = qt * (SEGS * SLEN) + seg * SLEN;   // padded timeline, < 2112

    // x rotation state + software pipeline over the scratch double-buffer.
    float4 cur0, cur1;
    {
        const int tc = (t0 > TT - 1) ? TT - 1 : t0;
        cur0 = px[2 * tc]; cur1 = px[2 * tc + 1];
    }
    float tvv[9];
    compute_tvv_rot(px, t0 + 1, cur0, cur1, sg, tvv);   // step 0 dx
    store_tvv(slotw, r, tvv);            // parity 0

    #pragma unroll 1
    for (int s = 0; s < SLEN - 1; ++s) {
        const int rpar = (s & 1) * 60;
        float Tri[45];
        load_tri(slot + rpar, Tri);                        // written 1 burst ago
        compute_tvv_rot(px, t0 + s + 2, cur0, cur1, sg, tvv); // step s+1 dx
        store_tvv(slotw + (60 - rpar), r, tvv);            // opposite parity
        taylor5(Tri, R01);
    }
    {
        float Tri[45];
        load_tri(slot + ((SLEN - 1) & 1) * 60, Tri);
        taylor5(Tri, R01);
    }

    // Scratch phase over; buf_s becomes the tree buffer.
    __syncthreads();

    // Store segment product: each active lane stores its pair of rows.
    if (act) {
        float* dst = &buf_s[seg * MATS];
        float4* d0 = reinterpret_cast<float4*>(dst + p0 * ROWP);
        d0[0] = make_float4(R01[0].x, R01[1].x, R01[2].x, R01[3].x);
        d0[1] = make_float4(R01[4].x, R01[5].x, R01[6].x, R01[7].x);
        d0[2] = make_float4(R01[8].x, R01[9].x, 0.0f, 0.0f);
        float4* d1 = reinterpret_cast<float4*>(dst + (p0 + 1) * ROWP);
        d1[0] = make_float4(R01[0].y, R01[1].y, R01[2].y, R01[3].y);
        d1[1] = make_float4(R01[4].y, R01[5].y, R01[6].y, R01[7].y);
        d1[2] = make_float4(R01[8].y, R01[9].y, 0.0f, 0.0f);
    }
    __syncthreads();

    // Dyadic tree on 96 leaves: spans 2..32 -> products at {0,32,64},
    // then (0*32) and (0*64) sequential tail (time order preserved).
    #pragma unroll 1
    for (int span = 2; span <= 32; span <<= 1) {
        const int np = SEGS / span;
        if (tid < 2 * np) {
            const int pr = tid >> 1;
            const int pq = tid & 1;
            pair_combine(buf_s, pr * span, pr * span + (span >> 1), pq);
        }
        __syncthreads();
    }
    if (tid < 2) pair_combine(buf_s, 0, 32, tid);
    __syncthreads();
    if (tid < 2) pair_combine(buf_s, 0, 64, tid);
    __syncthreads();

    // Chunk product -> ws, padded 120 floats at (chain*NCHK + qt)
    if (tid < 30) {
        const float4 v = reinterpret_cast<const float4*>(buf_s)[tid];
        reinterpret_cast<float4*>(ws)[((size_t)chain * NCHK + qt) * 30 + tid] = v;
    }
}

// K2: one block per chain; combine its 2 chunk products (time order)
__global__ __launch_bounds__(256)
void dev_tree2(const float* __restrict__ ws, float* __restrict__ out)
{
    __shared__ __align__(16) float buf_s[2 * MATS];
    const int tid   = threadIdx.x;
    const int chain = blockIdx.x;

    if (tid < 60) {
        const int m  = tid / 30;
        const int o4 = tid - m * 30;
        const float4 v = reinterpret_cast<const float4*>(ws)[((size_t)chain * 2 + m) * 30 + o4];
        reinterpret_cast<float4*>(&buf_s[m * MATS])[o4] = v;
    }
    __syncthreads();

    if (tid < 2)
        pair_combine(buf_s, 0, 1, tid);
    __syncthreads();

    if (tid < 100) {
        const int i = tid / 10;
        const int j = tid - i * 10;
        out[(size_t)chain * 100 + tid] = buf_s[i * ROWP + j];
    }
}

extern "C" void kernel_launch(void* const* d_in, const int* in_sizes, int n_in,
                              void* d_out, int out_size, void* d_ws, size_t ws_size,
                              hipStream_t stream) {
    (void)in_sizes; (void)n_in; (void)out_size; (void)ws_size;
    const float* x = (const float*)d_in[0];  // (64, 2048, 8)
    const float* A = (const float*)d_in[1];  // (2, 8, 10, 10)
    float* out = (float*)d_out;              // (64, 2, 10, 10)
    float* ws  = (float*)d_ws;               // 256 mats * 480 B = 122,880 B

    dev_serial<<<dim3(NCHAIN * NCHK), dim3(BLK), 0, stream>>>(x, A, ws);
    dev_tree2<<<dim3(NCHAIN), dim3(256), 0, stream>>>(ws, out);
}